// Round 1
// baseline (343.677 us; speedup 1.0000x reference)
//
#include <hip/hip_runtime.h>
#include <hip/hip_bf16.h>

// MHA forward: B=1, S=4096, D=1024, H=16, HD=64, causal, fp32 I/O, bf16 MFMA compute.
// Pipeline: cvt -> QKV gemm (scaled Q) -> flash attention -> Wo gemm.

typedef __bf16 bf16x8 __attribute__((ext_vector_type(8)));
typedef __bf16 bf16x4 __attribute__((ext_vector_type(4)));
typedef float f32x4 __attribute__((ext_vector_type(4)));

#define GAS __attribute__((address_space(1)))
#define LAS __attribute__((address_space(3)))

__device__ __forceinline__ void async_copy16(const void* g, void* l) {
  __builtin_amdgcn_global_load_lds((const GAS unsigned int*)g,
                                   (LAS unsigned int*)l, 16, 0, 0);
}

// ---------------- fp32 -> bf16 convert ----------------
__global__ __launch_bounds__(256) void cvt_f32_bf16(const float* __restrict__ src,
                                                    __bf16* __restrict__ dst, int n) {
  int i = (blockIdx.x * 256 + threadIdx.x) * 4;
  if (i < n) {
    float4 f = *(const float4*)(src + i);
    bf16x4 o;
    o[0] = (__bf16)f.x; o[1] = (__bf16)f.y; o[2] = (__bf16)f.z; o[3] = (__bf16)f.w;
    *(bf16x4*)(dst + i) = o;
  }
}

// ---------------- GEMM: C[M,N] = A[M,K] @ B[N,K]^T ----------------
// A,B bf16 row-major (K contiguous). 128x128 tile, BK=32, 256 thr (4 waves 2x2),
// m97 structure: global_load_lds width 16, 16x16x32 bf16 MFMA, 4x4 frags/wave.
template <typename CT, bool QSCALE>
__global__ __launch_bounds__(256) void gemm_bt(const __bf16* __restrict__ A,
                                               const __bf16* __restrict__ B,
                                               CT* __restrict__ C,
                                               int M, int N, int K) {
  __shared__ __bf16 As[128 * 32];
  __shared__ __bf16 Bs[128 * 32];
  const int tid = threadIdx.x;
  const int lane = tid & 63, wv = tid >> 6;
  const int l15 = lane & 15, quad = lane >> 4;
  const int wm = wv >> 1, wn = wv & 1;
  const int mbase = blockIdx.y * 128, nbase = blockIdx.x * 128;

  f32x4 acc[4][4] = {};

  for (int k0 = 0; k0 < K; k0 += 32) {
    __syncthreads();
#pragma unroll
    for (int q = 0; q < 2; ++q) {
      int i = q * 256 + tid;          // slot 0..511
      int row = i >> 2, kg = i & 3;   // 128 rows x 4 k-groups of 8 elems
      const __bf16* ga = A + (long)(mbase + row) * K + k0 + kg * 8;
      const __bf16* gb = B + (long)(nbase + row) * K + k0 + kg * 8;
      char* la = (char*)As + (q * 256 + wv * 64) * 16;  // wave-uniform base
      char* lb = (char*)Bs + (q * 256 + wv * 64) * 16;
      async_copy16(ga, la);
      async_copy16(gb, lb);
    }
    __syncthreads();
    bf16x8 af[4], bfr[4];
#pragma unroll
    for (int i = 0; i < 4; ++i)
      af[i] = *(const bf16x8*)&As[(wm * 64 + i * 16 + l15) * 32 + quad * 8];
#pragma unroll
    for (int j = 0; j < 4; ++j)
      bfr[j] = *(const bf16x8*)&Bs[(wn * 64 + j * 16 + l15) * 32 + quad * 8];
#pragma unroll
    for (int i = 0; i < 4; ++i)
#pragma unroll
      for (int j = 0; j < 4; ++j)
        acc[i][j] = __builtin_amdgcn_mfma_f32_16x16x32_bf16(af[i], bfr[j], acc[i][j], 0, 0, 0);
  }
  // epilogue: C row = quad*4+reg (+tile), col = l15 (+tile)
#pragma unroll
  for (int i = 0; i < 4; ++i)
#pragma unroll
    for (int j = 0; j < 4; ++j)
#pragma unroll
      for (int r = 0; r < 4; ++r) {
        int row = mbase + wm * 64 + i * 16 + quad * 4 + r;
        int col = nbase + wn * 64 + j * 16 + l15;
        float v = acc[i][j][r];
        if (QSCALE && col < 1024) v *= 0.125f;  // fold 1/sqrt(HD) into Q
        C[(long)row * N + col] = (CT)v;
      }
}

// ---------------- Flash attention ----------------
// QKV: [S, 3072] bf16 (cols 0..1023 Q (pre-scaled), 1024..2047 K, 2048..3071 V)
// O:   [S, 1024] bf16, layout out[s][h*64+d]
// block = 1 head x 64 Q-rows, 4 waves x 16 rows. K-tile = 64.
__global__ __launch_bounds__(256) void flash_attn(const __bf16* __restrict__ QKV,
                                                  __bf16* __restrict__ O) {
  const int bid = blockIdx.x;
  const int h = bid & 15;
  const int qb = 63 - (bid >> 4);   // heavy blocks first
  const int tid = threadIdx.x;
  const int w = tid >> 6;
  const int lane = tid & 63;
  const int l15 = lane & 15;
  const int quad = lane >> 4;
  const int hoff = h * 64;

  __shared__ __bf16 Ks[64][72];        // +16B pad: bank-balanced b128 reads
  __shared__ __bf16 Vt[64][72];        // V transposed: Vt[d][kt_row]
  __shared__ __bf16 Ps[4][16][72];     // per-wave P tile

  // Q fragments (A-layout), resident in regs for the whole block
  const int qrow = qb * 64 + w * 16 + l15;
  bf16x8 qf[2];
  qf[0] = *(const bf16x8*)(QKV + (long)qrow * 3072 + hoff + quad * 8);
  qf[1] = *(const bf16x8*)(QKV + (long)qrow * 3072 + hoff + 32 + quad * 8);

  float m_r[4], l_r[4];
  f32x4 o_acc[4] = {};
#pragma unroll
  for (int r = 0; r < 4; ++r) { m_r[r] = -3.0e38f; l_r[r] = 0.0f; }

  for (int kt = 0; kt <= qb; ++kt) {
    __syncthreads();
    // ---- stage K tile (row-major) and V tile (transposed) ----
    {
      const int rsub = tid >> 3, c8 = tid & 7;
#pragma unroll
      for (int p = 0; p < 2; ++p) {
        int rr = p * 32 + rsub;
        uint4 kd = *(const uint4*)(QKV + (long)(kt * 64 + rr) * 3072 + 1024 + hoff + c8 * 8);
        *(uint4*)&Ks[rr][c8 * 8] = kd;
      }
      // V: thread reads rows 2*rsub, 2*rsub+1 (cols c8*8..+7), writes packed pairs
      uint4 v0 = *(const uint4*)(QKV + (long)(kt * 64 + 2 * rsub) * 3072 + 2048 + hoff + c8 * 8);
      uint4 v1 = *(const uint4*)(QKV + (long)(kt * 64 + 2 * rsub + 1) * 3072 + 2048 + hoff + c8 * 8);
      const __bf16* a0 = (const __bf16*)&v0;
      const __bf16* a1 = (const __bf16*)&v1;
#pragma unroll
      for (int i = 0; i < 8; ++i) {
        union { __bf16 h2[2]; unsigned int u; } pk;
        pk.h2[0] = a0[i]; pk.h2[1] = a1[i];
        *(unsigned int*)&Vt[c8 * 8 + i][2 * rsub] = pk.u;
      }
    }
    __syncthreads();

    // ---- S = Q K^T (wave: rows w*16..+15 x cols 0..63) ----
    f32x4 sc[4] = {};
#pragma unroll
    for (int kk = 0; kk < 2; ++kk)
#pragma unroll
      for (int j = 0; j < 4; ++j) {
        bf16x8 kf = *(const bf16x8*)&Ks[j * 16 + l15][kk * 32 + quad * 8];
        sc[j] = __builtin_amdgcn_mfma_f32_16x16x32_bf16(qf[kk], kf, sc[j], 0, 0, 0);
      }

    // causal mask on diagonal tile
    if (kt == qb) {
#pragma unroll
      for (int j = 0; j < 4; ++j)
#pragma unroll
        for (int r = 0; r < 4; ++r) {
          int kcol = j * 16 + l15, qr = w * 16 + quad * 4 + r;
          if (kcol > qr) sc[j][r] = -3.0e38f;
        }
    }

    // ---- online softmax (rows = quad*4+r; reduce across 16 col-lanes) ----
    float mnew[4];
#pragma unroll
    for (int r = 0; r < 4; ++r) {
      float mx = fmaxf(fmaxf(sc[0][r], sc[1][r]), fmaxf(sc[2][r], sc[3][r]));
      mnew[r] = fmaxf(m_r[r], mx);
    }
#pragma unroll
    for (int mk = 1; mk < 16; mk <<= 1)
#pragma unroll
      for (int r = 0; r < 4; ++r)
        mnew[r] = fmaxf(mnew[r], __shfl_xor(mnew[r], mk));
    float alpha[4], rowsum[4];
#pragma unroll
    for (int r = 0; r < 4; ++r) {
      alpha[r] = __expf(m_r[r] - mnew[r]);
      m_r[r] = mnew[r];
      rowsum[r] = 0.0f;
    }
#pragma unroll
    for (int j = 0; j < 4; ++j)
#pragma unroll
      for (int r = 0; r < 4; ++r) {
        float p = __expf(sc[j][r] - mnew[r]);
        sc[j][r] = p;
        rowsum[r] += p;
      }
#pragma unroll
    for (int mk = 1; mk < 16; mk <<= 1)
#pragma unroll
      for (int r = 0; r < 4; ++r)
        rowsum[r] += __shfl_xor(rowsum[r], mk);
#pragma unroll
    for (int r = 0; r < 4; ++r) l_r[r] = l_r[r] * alpha[r] + rowsum[r];
#pragma unroll
    for (int j = 0; j < 4; ++j)
#pragma unroll
      for (int r = 0; r < 4; ++r) o_acc[j][r] *= alpha[r];

    // ---- P: C-layout regs -> LDS -> A-layout frags (m120 pattern) ----
#pragma unroll
    for (int j = 0; j < 4; ++j)
#pragma unroll
      for (int r = 0; r < 4; ++r)
        Ps[w][quad * 4 + r][j * 16 + l15] = (__bf16)sc[j][r];
    __builtin_amdgcn_s_waitcnt(0xc07f);  // lgkmcnt(0): own-wave LDS writes visible

    // ---- O += P @ V ----
#pragma unroll
    for (int kk = 0; kk < 2; ++kk) {
      bf16x8 pf = *(const bf16x8*)&Ps[w][l15][kk * 32 + quad * 8];
#pragma unroll
      for (int j = 0; j < 4; ++j) {
        bf16x8 vf = *(const bf16x8*)&Vt[j * 16 + l15][kk * 32 + quad * 8];
        o_acc[j] = __builtin_amdgcn_mfma_f32_16x16x32_bf16(pf, vf, o_acc[j], 0, 0, 0);
      }
    }
  }

  // ---- epilogue: normalize and store ----
#pragma unroll
  for (int r = 0; r < 4; ++r) {
    float inv = 1.0f / l_r[r];
#pragma unroll
    for (int j = 0; j < 4; ++j) {
      int row = qb * 64 + w * 16 + quad * 4 + r;
      int col = hoff + j * 16 + l15;
      O[(long)row * 1024 + col] = (__bf16)(o_acc[j][r] * inv);
    }
  }
}

// ---------------- launch ----------------
extern "C" void kernel_launch(void* const* d_in, const int* in_sizes, int n_in,
                              void* d_out, int out_size, void* d_ws, size_t ws_size,
                              hipStream_t stream) {
  const float* x  = (const float*)d_in[0];
  // d_in[1] = causal mask, structure known -> unused
  const float* Wq = (const float*)d_in[2];
  const float* Wk = (const float*)d_in[3];
  const float* Wv = (const float*)d_in[4];
  const float* Wo = (const float*)d_in[5];
  float* out = (float*)d_out;

  char* ws = (char*)d_ws;
  __bf16* xb  = (__bf16*)ws;                    // 8 MB  [4096,1024]
  __bf16* Wc  = (__bf16*)(ws + (8u << 20));     // 6 MB  [3072,1024] = [Wq;Wk;Wv]
  __bf16* Wob = (__bf16*)(ws + (14u << 20));    // 2 MB  [1024,1024]
  __bf16* QKV = (__bf16*)(ws + (16u << 20));    // 24 MB [4096,3072]
  __bf16* AO  = (__bf16*)(ws + (40u << 20));    // 8 MB  [4096,1024]

  cvt_f32_bf16<<<4096, 256, 0, stream>>>(x, xb, 1 << 22);
  cvt_f32_bf16<<<1024, 256, 0, stream>>>(Wq, Wc, 1 << 20);
  cvt_f32_bf16<<<1024, 256, 0, stream>>>(Wk, Wc + (1 << 20), 1 << 20);
  cvt_f32_bf16<<<1024, 256, 0, stream>>>(Wv, Wc + (2 << 20), 1 << 20);
  cvt_f32_bf16<<<1024, 256, 0, stream>>>(Wo, Wob, 1 << 20);

  dim3 g1(3072 / 128, 4096 / 128);
  gemm_bt<__bf16, true><<<g1, 256, 0, stream>>>(xb, Wc, QKV, 4096, 3072, 1024);

  flash_attn<<<1024, 256, 0, stream>>>(QKV, AO);

  dim3 g2(1024 / 128, 4096 / 128);
  gemm_bt<float, false><<<g2, 256, 0, stream>>>(AO, Wob, out, 4096, 1024, 1024);
}

// Round 2
// 322.764 us; speedup vs baseline: 1.0648x; 1.0648x over previous
//
#include <hip/hip_runtime.h>
#include <hip/hip_bf16.h>

// MHA forward: B=1, S=4096, D=1024, H=16, HD=64, causal, fp32 I/O, bf16 MFMA compute.
// Pipeline: cvt -> QKV gemm (Q scaled, V written transposed) -> flash attention -> Wo gemm.

typedef __bf16 bf16x8 __attribute__((ext_vector_type(8)));
typedef __bf16 bf16x4 __attribute__((ext_vector_type(4)));
typedef float f32x4 __attribute__((ext_vector_type(4)));

#define GAS __attribute__((address_space(1)))
#define LAS __attribute__((address_space(3)))

__device__ __forceinline__ void async_copy16(const void* g, void* l) {
  __builtin_amdgcn_global_load_lds((const GAS unsigned int*)g,
                                   (LAS unsigned int*)l, 16, 0, 0);
}

// ---------------- fp32 -> bf16 convert ----------------
__global__ __launch_bounds__(256) void cvt_f32_bf16(const float* __restrict__ src,
                                                    __bf16* __restrict__ dst, int n) {
  int i = (blockIdx.x * 256 + threadIdx.x) * 4;
  if (i < n) {
    float4 f = *(const float4*)(src + i);
    bf16x4 o;
    o[0] = (__bf16)f.x; o[1] = (__bf16)f.y; o[2] = (__bf16)f.z; o[3] = (__bf16)f.w;
    *(bf16x4*)(dst + i) = o;
  }
}

// ---------------- QKV GEMM: [4096,3072] = x[4096,1024] @ Wc[3072,1024]^T ----------------
// cols 0..1023   -> QK[:,0..1023]    (Q, scaled by 1/8)
// cols 1024..2047-> QK[:,1024..2047] (K)
// cols 2048..3071-> VT[col-2048][row] (V transposed)
__global__ __launch_bounds__(256) void gemm_qkv(const __bf16* __restrict__ A,
                                                const __bf16* __restrict__ B,
                                                __bf16* __restrict__ QK,
                                                __bf16* __restrict__ VT) {
  const int K = 1024;
  __shared__ __bf16 As[128 * 32];
  __shared__ __bf16 Bs[128 * 32];
  const int tid = threadIdx.x;
  const int lane = tid & 63, wv = tid >> 6;
  const int l15 = lane & 15, quad = lane >> 4;
  const int wm = wv >> 1, wn = wv & 1;
  const int mbase = blockIdx.y * 128, nbase = blockIdx.x * 128;

  f32x4 acc[4][4] = {};

  for (int k0 = 0; k0 < K; k0 += 32) {
    __syncthreads();
#pragma unroll
    for (int q = 0; q < 2; ++q) {
      int i = q * 256 + tid;
      int row = i >> 2, kg = i & 3;
      const __bf16* ga = A + (long)(mbase + row) * K + k0 + kg * 8;
      const __bf16* gb = B + (long)(nbase + row) * K + k0 + kg * 8;
      char* la = (char*)As + (q * 256 + wv * 64) * 16;
      char* lb = (char*)Bs + (q * 256 + wv * 64) * 16;
      async_copy16(ga, la);
      async_copy16(gb, lb);
    }
    __syncthreads();
    bf16x8 af[4], bfr[4];
#pragma unroll
    for (int i = 0; i < 4; ++i)
      af[i] = *(const bf16x8*)&As[(wm * 64 + i * 16 + l15) * 32 + quad * 8];
#pragma unroll
    for (int j = 0; j < 4; ++j)
      bfr[j] = *(const bf16x8*)&Bs[(wn * 64 + j * 16 + l15) * 32 + quad * 8];
#pragma unroll
    for (int i = 0; i < 4; ++i)
#pragma unroll
      for (int j = 0; j < 4; ++j)
        acc[i][j] = __builtin_amdgcn_mfma_f32_16x16x32_bf16(af[i], bfr[j], acc[i][j], 0, 0, 0);
  }

  if (nbase >= 2048) {
    // V block: write transposed VT[vcol][row]
#pragma unroll
    for (int i = 0; i < 4; ++i)
#pragma unroll
      for (int j = 0; j < 4; ++j) {
        int vcol = nbase - 2048 + wn * 64 + j * 16 + l15;
        int row = mbase + wm * 64 + i * 16 + quad * 4;
        union { __bf16 b[4]; uint2 u; } pk;
#pragma unroll
        for (int r = 0; r < 4; ++r) pk.b[r] = (__bf16)acc[i][j][r];
        *(uint2*)(VT + (long)vcol * 4096 + row) = pk.u;
      }
  } else {
#pragma unroll
    for (int i = 0; i < 4; ++i)
#pragma unroll
      for (int j = 0; j < 4; ++j) {
        int col = nbase + wn * 64 + j * 16 + l15;
        float s = (col < 1024) ? 0.125f : 1.0f;
#pragma unroll
        for (int r = 0; r < 4; ++r) {
          int row = mbase + wm * 64 + i * 16 + quad * 4 + r;
          QK[(long)row * 2048 + col] = (__bf16)(acc[i][j][r] * s);
        }
      }
  }
}

// ---------------- Wo GEMM: out[4096,1024] = AO[4096,1024] @ Wo[1024,1024]^T (fp32 out) ----------------
__global__ __launch_bounds__(256) void gemm_wo(const __bf16* __restrict__ A,
                                               const __bf16* __restrict__ B,
                                               float* __restrict__ C) {
  const int K = 1024, N = 1024;
  __shared__ __bf16 As[128 * 32];
  __shared__ __bf16 Bs[128 * 32];
  const int tid = threadIdx.x;
  const int lane = tid & 63, wv = tid >> 6;
  const int l15 = lane & 15, quad = lane >> 4;
  const int wm = wv >> 1, wn = wv & 1;
  const int mbase = blockIdx.y * 128, nbase = blockIdx.x * 128;

  f32x4 acc[4][4] = {};

  for (int k0 = 0; k0 < K; k0 += 32) {
    __syncthreads();
#pragma unroll
    for (int q = 0; q < 2; ++q) {
      int i = q * 256 + tid;
      int row = i >> 2, kg = i & 3;
      const __bf16* ga = A + (long)(mbase + row) * K + k0 + kg * 8;
      const __bf16* gb = B + (long)(nbase + row) * K + k0 + kg * 8;
      char* la = (char*)As + (q * 256 + wv * 64) * 16;
      char* lb = (char*)Bs + (q * 256 + wv * 64) * 16;
      async_copy16(ga, la);
      async_copy16(gb, lb);
    }
    __syncthreads();
    bf16x8 af[4], bfr[4];
#pragma unroll
    for (int i = 0; i < 4; ++i)
      af[i] = *(const bf16x8*)&As[(wm * 64 + i * 16 + l15) * 32 + quad * 8];
#pragma unroll
    for (int j = 0; j < 4; ++j)
      bfr[j] = *(const bf16x8*)&Bs[(wn * 64 + j * 16 + l15) * 32 + quad * 8];
#pragma unroll
    for (int i = 0; i < 4; ++i)
#pragma unroll
      for (int j = 0; j < 4; ++j)
        acc[i][j] = __builtin_amdgcn_mfma_f32_16x16x32_bf16(af[i], bfr[j], acc[i][j], 0, 0, 0);
  }
#pragma unroll
  for (int i = 0; i < 4; ++i)
#pragma unroll
    for (int j = 0; j < 4; ++j)
#pragma unroll
      for (int r = 0; r < 4; ++r) {
        int row = mbase + wm * 64 + i * 16 + quad * 4 + r;
        int col = nbase + wn * 64 + j * 16 + l15;
        C[(long)row * N + col] = acc[i][j][r];
      }
}

// ---------------- Flash attention ----------------
// QK: [4096,2048] bf16 (cols 0..1023 Q pre-scaled, 1024..2047 K)
// VT: [1024,4096] bf16 (V transposed: VT[h*64+d][s])
// AO: [4096,1024] bf16
// Block (h,p): processes q-tiles qb=63-p then qb=p -> uniform 65 kt-iterations.
// 4 waves x 16 q-rows, kt-tile 64. K/V^T staged via global_load_lds into
// half-split [2][64][32] layout (b128 frag reads at the 8-way b128 minimum).
__global__ __launch_bounds__(256) void flash_attn(const __bf16* __restrict__ QK,
                                                  const __bf16* __restrict__ VT,
                                                  __bf16* __restrict__ AO) {
  const int bid = blockIdx.x;
  const int h = bid & 15;
  const int p = bid >> 4;           // 0..31
  const int tid = threadIdx.x;
  const int w = tid >> 6;
  const int lane = tid & 63;
  const int l15 = lane & 15;
  const int quad = lane >> 4;
  const int hoff = h * 64;

  __shared__ __bf16 Ks[2][64][32];  // [half of d][kt-row][32 d]
  __shared__ __bf16 Vs[2][64][32];  // [half of kt][d-row][32 kt]
  __shared__ __bf16 Ps[4][16][68];  // per-wave P; stride 68: 2-way stores, 4-way reads

  const int lr = lane >> 2;         // 0..15: half-row within staging chunk
  const int lc = lane & 3;          // 16B granule within 64B half-row

  for (int pass = 0; pass < 2; ++pass) {
    const int qb = pass ? p : 63 - p;
    const int qrow = qb * 64 + w * 16 + l15;
    bf16x8 qf[2];
    qf[0] = *(const bf16x8*)(QK + (long)qrow * 2048 + hoff + quad * 8);
    qf[1] = *(const bf16x8*)(QK + (long)qrow * 2048 + hoff + 32 + quad * 8);

    float m_r[4], l_r[4];
    f32x4 o_acc[4] = {};
#pragma unroll
    for (int r = 0; r < 4; ++r) { m_r[r] = -3.0e38f; l_r[r] = 0.0f; }

    for (int kt = 0; kt <= qb; ++kt) {
      const int ktb = kt * 64;
      __syncthreads();  // all waves done reading previous K/V tiles
#pragma unroll
      for (int t = 0; t < 2; ++t) {
        int e = t * 4 + w;              // 0..7 issue slot
        int hh = e & 1;                 // which 32-elem half
        int rbase = (e >> 1) * 16;      // 16 rows per issue
        int r = rbase + lr;
        // K rows ktb+r, d-half hh
        async_copy16(QK + (long)(ktb + r) * 2048 + 1024 + hoff + hh * 32 + lc * 8,
                     (char*)&Ks[hh][rbase][0]);
        // V^T rows hoff+r (d), kt-half hh
        async_copy16(VT + (long)(hoff + r) * 4096 + ktb + hh * 32 + lc * 8,
                     (char*)&Vs[hh][rbase][0]);
      }
      __syncthreads();  // staging complete

      // ---- S = Q K^T ----
      f32x4 sc[4] = {};
#pragma unroll
      for (int kk = 0; kk < 2; ++kk)
#pragma unroll
        for (int j = 0; j < 4; ++j) {
          bf16x8 kf = *(const bf16x8*)&Ks[kk][j * 16 + l15][quad * 8];
          sc[j] = __builtin_amdgcn_mfma_f32_16x16x32_bf16(qf[kk], kf, sc[j], 0, 0, 0);
        }

      // causal mask on diagonal tile
      if (kt == qb) {
#pragma unroll
        for (int j = 0; j < 4; ++j)
#pragma unroll
          for (int r = 0; r < 4; ++r) {
            int kcol = j * 16 + l15, qr = w * 16 + quad * 4 + r;
            if (kcol > qr) sc[j][r] = -3.0e38f;
          }
      }

      // ---- online softmax (rows = quad*4+r; reduce across 16 col-lanes) ----
      float mnew[4];
#pragma unroll
      for (int r = 0; r < 4; ++r) {
        float mx = fmaxf(fmaxf(sc[0][r], sc[1][r]), fmaxf(sc[2][r], sc[3][r]));
        mnew[r] = fmaxf(m_r[r], mx);
      }
#pragma unroll
      for (int mk = 1; mk < 16; mk <<= 1)
#pragma unroll
        for (int r = 0; r < 4; ++r)
          mnew[r] = fmaxf(mnew[r], __shfl_xor(mnew[r], mk));
      float alpha[4], rowsum[4];
#pragma unroll
      for (int r = 0; r < 4; ++r) {
        alpha[r] = __expf(m_r[r] - mnew[r]);
        m_r[r] = mnew[r];
        rowsum[r] = 0.0f;
      }
#pragma unroll
      for (int j = 0; j < 4; ++j)
#pragma unroll
        for (int r = 0; r < 4; ++r) {
          float pv = __expf(sc[j][r] - mnew[r]);
          sc[j][r] = pv;
          rowsum[r] += pv;
        }
#pragma unroll
      for (int mk = 1; mk < 16; mk <<= 1)
#pragma unroll
        for (int r = 0; r < 4; ++r)
          rowsum[r] += __shfl_xor(rowsum[r], mk);
#pragma unroll
      for (int r = 0; r < 4; ++r) l_r[r] = l_r[r] * alpha[r] + rowsum[r];
#pragma unroll
      for (int j = 0; j < 4; ++j)
#pragma unroll
        for (int r = 0; r < 4; ++r) o_acc[j][r] *= alpha[r];

      // ---- P: C-layout regs -> per-wave LDS -> A-layout frags ----
#pragma unroll
      for (int j = 0; j < 4; ++j)
#pragma unroll
        for (int r = 0; r < 4; ++r)
          Ps[w][quad * 4 + r][j * 16 + l15] = (__bf16)sc[j][r];
      __builtin_amdgcn_s_waitcnt(0xc07f);  // lgkmcnt(0): own-wave LDS writes visible

      // ---- O += P @ V ----
#pragma unroll
      for (int kk = 0; kk < 2; ++kk) {
        bf16x8 pf = *(const bf16x8*)&Ps[w][l15][kk * 32 + quad * 8];
#pragma unroll
        for (int j = 0; j < 4; ++j) {
          bf16x8 vf = *(const bf16x8*)&Vs[kk][j * 16 + l15][quad * 8];
          o_acc[j] = __builtin_amdgcn_mfma_f32_16x16x32_bf16(pf, vf, o_acc[j], 0, 0, 0);
        }
      }
    }

    // ---- epilogue: normalize and store ----
#pragma unroll
    for (int r = 0; r < 4; ++r) {
      float inv = 1.0f / l_r[r];
#pragma unroll
      for (int j = 0; j < 4; ++j) {
        int row = qb * 64 + w * 16 + quad * 4 + r;
        int col = hoff + j * 16 + l15;
        AO[(long)row * 1024 + col] = (__bf16)(o_acc[j][r] * inv);
      }
    }
  }
}

// ---------------- launch ----------------
extern "C" void kernel_launch(void* const* d_in, const int* in_sizes, int n_in,
                              void* d_out, int out_size, void* d_ws, size_t ws_size,
                              hipStream_t stream) {
  const float* x  = (const float*)d_in[0];
  // d_in[1] = causal mask (structure known -> unused)
  const float* Wq = (const float*)d_in[2];
  const float* Wk = (const float*)d_in[3];
  const float* Wv = (const float*)d_in[4];
  const float* Wo = (const float*)d_in[5];
  float* out = (float*)d_out;

  char* ws = (char*)d_ws;
  __bf16* xb  = (__bf16*)ws;                    // 8 MB  [4096,1024]
  __bf16* Wc  = (__bf16*)(ws + (8u << 20));     // 6 MB  [3072,1024] = [Wq;Wk;Wv]
  __bf16* Wob = (__bf16*)(ws + (14u << 20));    // 2 MB  [1024,1024]
  __bf16* QK  = (__bf16*)(ws + (16u << 20));    // 16 MB [4096,2048]
  __bf16* VT  = (__bf16*)(ws + (32u << 20));    // 8 MB  [1024,4096]
  __bf16* AO  = (__bf16*)(ws + (40u << 20));    // 8 MB  [4096,1024]

  cvt_f32_bf16<<<4096, 256, 0, stream>>>(x, xb, 1 << 22);
  cvt_f32_bf16<<<1024, 256, 0, stream>>>(Wq, Wc, 1 << 20);
  cvt_f32_bf16<<<1024, 256, 0, stream>>>(Wk, Wc + (1 << 20), 1 << 20);
  cvt_f32_bf16<<<1024, 256, 0, stream>>>(Wv, Wc + (2 << 20), 1 << 20);
  cvt_f32_bf16<<<1024, 256, 0, stream>>>(Wo, Wob, 1 << 20);

  dim3 g1(3072 / 128, 4096 / 128);
  gemm_qkv<<<g1, 256, 0, stream>>>(xb, Wc, QK, VT);

  flash_attn<<<512, 256, 0, stream>>>(QK, VT, AO);

  dim3 g2(1024 / 128, 4096 / 128);
  gemm_wo<<<g2, 256, 0, stream>>>(AO, Wob, out);
}